// Round 8
// baseline (434.515 us; speedup 1.0000x reference)
//
#include <hip/hip_runtime.h>
#include <cmath>

#define LDIM 4096
#define CDIM 768
#define BDIM 2
#define NST 4
#define RNK 48
#define CH 64     // scan chunks per sequence
#define LC 64     // chunk length (CH*LC == LDIM)
#define NDT 896   // widened dt-GEMM N: 768 dt cols + 8 B/C cols + 120 zero pad (7 x 128)

typedef short bf16x8 __attribute__((ext_vector_type(8)));
typedef short bf16x4 __attribute__((ext_vector_type(4)));
typedef float f32x4 __attribute__((ext_vector_type(4)));

__device__ __forceinline__ float sigmoidf_(float x) { return 1.f / (1.f + __expf(-x)); }

__device__ __forceinline__ unsigned short f2bf(float f) {
    unsigned int u = __float_as_uint(f);
    u += 0x7fffu + ((u >> 16) & 1u);
    return (unsigned short)(u >> 16);
}
__device__ __forceinline__ float bf2f(unsigned short us) {
    unsigned int u = ((unsigned int)us) << 16;
    return __uint_as_float(u);
}

__device__ __forceinline__ void llds16(const unsigned short* g, unsigned short* l) {
    __builtin_amdgcn_global_load_lds(
        (const __attribute__((address_space(1))) unsigned int*)g,
        (__attribute__((address_space(3))) unsigned int*)l, 16, 0, 0);
}

// ---------- fused prep: stats (LN mean/rstd) + weight transposes + wcomb, one launch ----------
// grid.x partition: [0,256) stats | [256,1408) wt-transpose (24x12x4) | [1408,1744) wcomb (12x14x2)
__global__ __launch_bounds__(256) void prep_kernel(
    const float* __restrict__ x0, const float* __restrict__ x1, float* __restrict__ stats,
    const float* __restrict__ Win0, const float* __restrict__ Win1,
    const float* __restrict__ Wout0, const float* __restrict__ Wout1,
    unsigned short* __restrict__ WinT0, unsigned short* __restrict__ WinT1,
    unsigned short* __restrict__ WoutT0, unsigned short* __restrict__ WoutT1,
    const float* __restrict__ Wxp0, const float* __restrict__ Wdt0,
    const float* __restrict__ Wxp1, const float* __restrict__ Wdt1,
    unsigned short* __restrict__ Wc0, unsigned short* __restrict__ Wc1)
{
    __shared__ float smem[64 * 65];
    int bid = blockIdx.x;
    int t = threadIdx.x;

    if (bid < 256) {
        // ---- LN stats: s(1) b(1) lgroup(6)
        int s = bid >> 7;
        int b = (bid >> 6) & 1;
        int l0 = (bid & 63) * 64;
        int wave = t >> 6, lane = t & 63;
        const float* x = s ? x1 : x0;
        const float* xp = x + ((size_t)b * CDIM) * LDIM + l0 + lane;
        float sm = 0.f, sq = 0.f;
        int cbeg = wave * 192;
#pragma unroll
        for (int i0 = 0; i0 < 192; i0 += 16) {
            float v[16];
#pragma unroll
            for (int j = 0; j < 16; j++) v[j] = xp[(size_t)(cbeg + i0 + j) * LDIM];
#pragma unroll
            for (int j = 0; j < 16; j++) { sm += v[j]; sq += v[j] * v[j]; }
        }
        float* red = smem;  // [2][4][64]
        red[(0 * 4 + wave) * 64 + lane] = sm;
        red[(1 * 4 + wave) * 64 + lane] = sq;
        __syncthreads();
        if (wave == 0) {
            float s_ = red[lane] + red[64 + lane] + red[128 + lane] + red[192 + lane];
            float q_ = red[256 + lane] + red[320 + lane] + red[384 + lane] + red[448 + lane];
            float m = s_ * (1.f / CDIM);
            float var = q_ * (1.f / CDIM) - m * m;
            int idx = s * 8192 + b * LDIM + l0 + lane;
            stats[2 * idx] = m;
            stats[2 * idx + 1] = rsqrtf(var + 1e-5f);
        }
        return;
    }
    if (bid < 1408) {
        // ---- weight transpose: z=0,1 Win (768x1536)->WinT; z=2,3 Wout (768x768)->WoutT
        int b2 = bid - 256;
        int bx = b2 % 24, by = (b2 / 24) % 12, z = b2 / 288;
        const float* W = (z == 0) ? Win0 : (z == 1) ? Win1 : (z == 2) ? Wout0 : Wout1;
        unsigned short* Wt = (z == 0) ? WinT0 : (z == 1) ? WinT1 : (z == 2) ? WoutT0 : WoutT1;
        const int K = CDIM;
        const int N = (z < 2) ? 2 * CDIM : CDIM;
        if (bx * 64 >= N) return;  // block-uniform
        float (*tile)[65] = (float(*)[65])smem;
        int n0 = bx * 64, k0 = by * 64;
        int tn = t & 63, tg = t >> 6;
#pragma unroll
        for (int i = 0; i < 16; i++) {
            int kl = tg * 16 + i;
            tile[kl][tn] = W[(size_t)(k0 + kl) * N + n0 + tn];
        }
        __syncthreads();
#pragma unroll
        for (int i = 0; i < 16; i++) {
            int nl = tg * 16 + i;
            int k = k0 + tn, n = n0 + nl;
            Wt[(size_t)n * K + k] = f2bf(tile[tn][nl]);
        }
        return;
    }
    // ---- wcomb: rows 0..767 = (Wxp[:, :48] @ Wdt)^T; 768..775 = Wxp B/C cols; 776..895 = 0
    {
        int b3 = bid - 1408;
        int bx = b3 % 12, by = (b3 / 12) % 14, s = b3 / 168;
        const float* Wxp = s ? Wxp1 : Wxp0;
        const float* Wdt = s ? Wdt1 : Wdt0;
        unsigned short* WcombT = s ? Wc1 : Wc0;
        int k = bx * 64 + (t & 63);
        int n0 = by * 64;
        float wx[RNK];
#pragma unroll
        for (int r = 0; r < RNK; r++) wx[r] = Wxp[k * 56 + r];
        for (int i = (t >> 6); i < 64; i += 4) {
            int n = n0 + i;
            float val;
            if (n < CDIM) {
                float acc = 0.f;
#pragma unroll
                for (int r = 0; r < RNK; r++) acc += wx[r] * Wdt[(size_t)r * CDIM + n];
                val = acc;
            } else if (n < CDIM + 8) {
                val = Wxp[k * 56 + RNK + (n - CDIM)];
            } else {
                val = 0.f;
            }
            WcombT[(size_t)n * CDIM + k] = f2bf(val);
        }
    }
}

// ---------- transpose + LN: x (B,C,L) -> xn bf16 (B*L, C); raw x -> d_out (residual pre-store) ----------
__global__ __launch_bounds__(256) void transpose_ln_kernel(
    const float* __restrict__ x0, const float* __restrict__ x1,
    const float* __restrict__ g0, const float* __restrict__ bb0,
    const float* __restrict__ g1, const float* __restrict__ bb1,
    const float* __restrict__ stats,
    unsigned short* __restrict__ xnb0, unsigned short* __restrict__ xnb1,
    float* __restrict__ out)
{
    __shared__ float tile[64][65];
    int t = threadIdx.x;
    int c0 = blockIdx.x * 64, l0 = blockIdx.y * 64;
    int z = blockIdx.z;
    int s = z >> 1, b = z & 1;
    const float* x = s ? x1 : x0;
    const float* g = s ? g1 : g0;
    const float* bb = s ? bb1 : bb0;
    unsigned short* xnb = s ? xnb1 : xnb0;
    int lane16 = t & 15, cg = t >> 4;  // 16 l-quads x 16 c-groups
#pragma unroll
    for (int i = 0; i < 4; i++) {
        int cl = cg + 16 * i;
        f32x4 v = *(const f32x4*)&x[((size_t)(b * CDIM + c0 + cl)) * LDIM + l0 + lane16 * 4];
#pragma unroll
        for (int j = 0; j < 4; j++) tile[cl][lane16 * 4 + j] = v[j];
    }
    __syncthreads();
    const size_t SZ = (size_t)BDIM * LDIM * CDIM;
    int tl = t & 63, tg = t >> 6;
#pragma unroll
    for (int i = 0; i < 16; i++) {
        int ll = tg * 16 + i;
        int l = l0 + ll, c = c0 + tl;
        float v = tile[tl][ll];
        int sidx = s * 8192 + b * LDIM + l;
        float m = stats[sidx * 2], rs = stats[sidx * 2 + 1];
        size_t o = ((size_t)(b * LDIM + l)) * CDIM + c;
        out[(size_t)s * SZ + o] = v;  // residual pre-store
        xnb[o] = f2bf((v - m) * rs * g[c] + bb[c]);
    }
}

// ---------- bf16 MFMA GEMM: the measured-best (74us in_proj) config, unchanged from R7 ----------
// 512 threads, 8 waves (2M x 4N) of 64x32; 128x128 tile; BK=32; 3-stage pipeline; 48KB LDS
// -> 3 blocks/CU (measured: 46% occupancy, 40 VGPR, 0 bank conflicts).
// Counted vmcnt exact: at iter top outstanding = tiles i,i+1 (4 loads); vmcnt(2) drains tile i
// while i+1 stays in flight; barrier publishes; ISSUE(i+2) overwrites stage whose reads drained.
// Swizzle (HW-verified, 0 conflicts): slot chunk = global chunk ^ ((row>>1)&3).
__global__ __launch_bounds__(512, 4) void gemm_mfma(
    const unsigned short* __restrict__ A0, const unsigned short* __restrict__ A1,
    const unsigned short* __restrict__ Bt0, const unsigned short* __restrict__ Bt1,
    void* __restrict__ C0, void* __restrict__ C1, int ldc, int K, int epi,
    const float* __restrict__ bias0, const float* __restrict__ bias1,
    float* __restrict__ D0, float* __restrict__ D1)
{
    const unsigned short* A = blockIdx.z ? A1 : A0;
    const unsigned short* Bt = blockIdx.z ? Bt1 : Bt0;
    void* C = blockIdx.z ? C1 : C0;
    const float* bias = blockIdx.z ? bias1 : bias0;
    float* D = blockIdx.z ? D1 : D0;

    __shared__ unsigned short As[3][128 * 32];
    __shared__ unsigned short Bs[3][128 * 32];
    const int tid = threadIdx.x;
    const int wave = tid >> 6, lane = tid & 63;
    const int row0 = blockIdx.x * 128, col0 = blockIdx.y * 128;
    const int wm = (wave >> 2) * 64, wn = (wave & 3) * 32;   // 2x4 wave grid, 64x32 per wave
    f32x4 acc[4][2] = {};
    const int lr = lane >> 2;                                // staging row within wave's 16
    const int gi = ((lane & 3) ^ ((lane >> 3) & 3)) * 8;     // swizzled global k-chunk
    const int fr = lane & 15, fc = lane >> 4;                // fragment row / k-chunk

    const unsigned short* ga0 = A + (size_t)(row0 + wave * 16 + lr) * K + gi;
    const unsigned short* gb0 = Bt + (size_t)(col0 + wave * 16 + lr) * K + gi;
    const int rb = wave * 16;

#define ISSUE(st, kb)                         \
    do {                                      \
        llds16(ga0 + (kb), &As[st][rb * 32]); \
        llds16(gb0 + (kb), &Bs[st][rb * 32]); \
    } while (0)

    const int NIT = K / 32;
    ISSUE(0, 0);
    ISSUE(1, 32);
    for (int i = 0; i < NIT; i++) {
        if (i < NIT - 1) __builtin_amdgcn_s_waitcnt(0xF72);  // vmcnt(2): tile i landed, i+1 in flight
        else __builtin_amdgcn_s_waitcnt(0xF70);              // vmcnt(0): last tile
        __builtin_amdgcn_s_barrier();
        if (i + 2 < NIT) ISSUE((i + 2) % 3, (i + 2) * 32);
        const unsigned short* as = As[i % 3];
        const unsigned short* bs = Bs[i % 3];
        bf16x8 af[4], bfr[2];
#pragma unroll
        for (int ii = 0; ii < 4; ii++) {
            int r = wm + ii * 16 + fr;
            af[ii] = *(const bf16x8*)&as[r * 32 + (fc ^ ((r >> 1) & 3)) * 8];
        }
#pragma unroll
        for (int j = 0; j < 2; j++) {
            int r = wn + j * 16 + fr;
            bfr[j] = *(const bf16x8*)&bs[r * 32 + (fc ^ ((r >> 1) & 3)) * 8];
        }
#pragma unroll
        for (int ii = 0; ii < 4; ii++)
#pragma unroll
            for (int j = 0; j < 2; j++)
                acc[ii][j] = __builtin_amdgcn_mfma_f32_16x16x32_bf16(af[ii], bfr[j], acc[ii][j], 0, 0, 0);
    }
#undef ISSUE

    const int cr = (lane >> 4) * 4, cc = lane & 15;
#pragma unroll
    for (int ii = 0; ii < 4; ii++)
#pragma unroll
        for (int j = 0; j < 2; j++) {
            int col = col0 + wn + j * 16 + cc;
#pragma unroll
            for (int r = 0; r < 4; r++) {
                int row = row0 + wm + ii * 16 + cr + r;
                float v = acc[ii][j][r];
                if (epi == 1) {
                    float* Cf = (float*)C;
                    size_t o = (size_t)row * ldc + col;
                    Cf[o] = v + Cf[o];
                } else if (epi == 2) {
                    if (col < CDIM) {
                        v += bias[col];
                        v = (v > 20.f) ? v : __logf(1.f + __expf(v));
                        ((unsigned short*)C)[(size_t)row * ldc + col] = f2bf(v);
                    } else if (col < CDIM + 8) {
                        D[(size_t)row * 8 + (col - CDIM)] = v;  // fused B/C projection -> dbl
                    }
                } else {
                    ((unsigned short*)C)[(size_t)row * ldc + col] = f2bf(v);
                }
            }
        }
}

// ---------- depthwise causal conv (K=4) + SiLU; 4 l's x 8 d's per thread ----------
// Tap-row register reuse: 7 row-loads produce 4 outputs (1.75 loads/output vs 4 before).
__global__ __launch_bounds__(256) void conv_silu_kernel(
    const unsigned short* __restrict__ uzb0, const unsigned short* __restrict__ uzb1,
    const float* __restrict__ w0, const float* __restrict__ bc0,
    const float* __restrict__ w1, const float* __restrict__ bc1,
    unsigned short* __restrict__ ub0, unsigned short* __restrict__ ub1)
{
    int s = blockIdx.y;
    const unsigned short* uzb = s ? uzb1 : uzb0;
    const float* w = s ? w1 : w0;
    const float* bc = s ? bc1 : bc0;
    unsigned short* ub = s ? ub1 : ub0;
    int idx = blockIdx.x * 256 + threadIdx.x;  // over M*CDIM/32
    int d8 = (idx % 96) * 8;
    int bl0 = (idx / 96) * 4;
    int l0 = bl0 & (LDIM - 1);

    float wr[8][4];
#pragma unroll
    for (int q = 0; q < 8; q++) {
        f32x4 wv = *(const f32x4*)&w[(d8 + q) * 4];
#pragma unroll
        for (int k = 0; k < 4; k++) wr[q][k] = wv[k];
    }
    f32x4 b0 = *(const f32x4*)&bc[d8];
    f32x4 b1 = *(const f32x4*)&bc[d8 + 4];

    // tap rows j=0..6 correspond to token bl0-3+j; j>=3 always in-bounds
    bf16x8 rows[7];
#pragma unroll
    for (int j = 0; j < 7; j++) {
        int ls = l0 - 3 + j;
        if (ls >= 0)
            rows[j] = *(const bf16x8*)&uzb[(size_t)(bl0 - 3 + j) * (2 * CDIM) + d8];
        else
            rows[j] = bf16x8{};
    }

#pragma unroll
    for (int li = 0; li < 4; li++) {
        float acc[8];
#pragma unroll
        for (int q = 0; q < 4; q++) { acc[q] = b0[q]; acc[4 + q] = b1[q]; }
#pragma unroll
        for (int k = 0; k < 4; k++) {
#pragma unroll
            for (int q = 0; q < 8; q++)
                acc[q] += bf2f((unsigned short)rows[li + k][q]) * wr[q][k];
        }
        bf16x8 ov;
#pragma unroll
        for (int q = 0; q < 8; q++) {
            float v = acc[q];
            ov[q] = (short)f2bf(v * sigmoidf_(v));
        }
        *(bf16x8*)&ub[(size_t)(bl0 + li) * CDIM + d8] = ov;
    }
}

// ---------- chunked selective scan; u/dt/z bf16, 4 d's per thread (8B loads, G13) ----------
__global__ __launch_bounds__(256) void scan_phaseA(
    const unsigned short* __restrict__ u0, const unsigned short* __restrict__ dt0,
    const float* __restrict__ dbl0, const float* __restrict__ Alog0,
    const unsigned short* __restrict__ u1, const unsigned short* __restrict__ dt1,
    const float* __restrict__ dbl1, const float* __restrict__ Alog1,
    float* __restrict__ agg)
{
    int idx = blockIdx.x * 256 + threadIdx.x;  // over 2*2*64*192
    int dp = idx % 192;
    int d0 = dp * 4;
    int t1 = idx / 192;
    int c = t1 % CH;
    int t2 = t1 / CH;
    int b = t2 & 1;
    int s = t2 >> 1;
    const unsigned short* u = s ? u1 : u0;
    const unsigned short* dt = s ? dt1 : dt0;
    const float* dbl = s ? dbl1 : dbl0;
    const float* Alog = s ? Alog1 : Alog0;
    float A[4][4];
#pragma unroll
    for (int j = 0; j < 4; j++)
#pragma unroll
        for (int n = 0; n < 4; n++) A[j][n] = -__expf(Alog[(d0 + j) * 4 + n]);
    float h[4][4] = {}, aa[4][4];
#pragma unroll
    for (int j = 0; j < 4; j++)
#pragma unroll
        for (int n = 0; n < 4; n++) aa[j][n] = 1.f;
    int rowb = b * LDIM + c * LC;
    for (int t = 0; t < LC; t++) {
        int row = rowb + t;
        bf16x4 up = *(const bf16x4*)&u[(size_t)row * CDIM + d0];
        bf16x4 dtp = *(const bf16x4*)&dt[(size_t)row * CDIM + d0];
        const float* bm = dbl + (size_t)row * 8;
#pragma unroll
        for (int j = 0; j < 4; j++) {
            float uv = bf2f((unsigned short)up[j]);
            float dtv = bf2f((unsigned short)dtp[j]);
            float du = dtv * uv;
#pragma unroll
            for (int n = 0; n < 4; n++) {
                float dA = __expf(dtv * A[j][n]);
                h[j][n] = dA * h[j][n] + du * bm[n];
                aa[j][n] *= dA;
            }
        }
    }
    size_t base = ((size_t)(s * 2 + b) * CH + c) * CDIM + d0;
#pragma unroll
    for (int j = 0; j < 4; j++) {
        float* o = agg + (base + j) * 8;
#pragma unroll
        for (int n = 0; n < 4; n++) { o[n] = aa[j][n]; o[4 + n] = h[j][n]; }
    }
}

// one thread per (sb, d, n): 12288 threads / 48 blocks (4x the parallelism of per-(sb,d))
__global__ __launch_bounds__(256) void scan_phaseB(const float* __restrict__ agg,
                                                   float* __restrict__ hinit)
{
    int idx = blockIdx.x * 256 + threadIdx.x;  // over 4*768*4
    int n = idx & 3;
    int d = (idx >> 2) % CDIM;
    int sb = idx / (CDIM * 4);
    float st = 0.f;
    for (int c = 0; c < CH; c++) {
        size_t base = ((size_t)sb * CH + c) * CDIM + d;
        hinit[base * 4 + n] = st;
        st = agg[base * 8 + n] * st + agg[base * 8 + 4 + n];
    }
}

__global__ __launch_bounds__(256) void scan_phaseC(
    const unsigned short* __restrict__ u0, const unsigned short* __restrict__ dt0,
    const unsigned short* __restrict__ uzb0, const float* __restrict__ dbl0,
    const float* __restrict__ Alog0, const float* __restrict__ Dsk0, unsigned short* __restrict__ g0,
    const unsigned short* __restrict__ u1, const unsigned short* __restrict__ dt1,
    const unsigned short* __restrict__ uzb1, const float* __restrict__ dbl1,
    const float* __restrict__ Alog1, const float* __restrict__ Dsk1, unsigned short* __restrict__ g1,
    const float* __restrict__ hinit)
{
    int idx = blockIdx.x * 256 + threadIdx.x;  // over 2*2*64*192
    int dp = idx % 192;
    int d0 = dp * 4;
    int t1 = idx / 192;
    int c = t1 % CH;
    int t2 = t1 / CH;
    int b = t2 & 1;
    int s = t2 >> 1;
    const unsigned short* u = s ? u1 : u0;
    const unsigned short* dt = s ? dt1 : dt0;
    const unsigned short* uzb = s ? uzb1 : uzb0;
    const float* dbl = s ? dbl1 : dbl0;
    const float* dblO = s ? dbl0 : dbl1;  // cross: other stream's C projection
    const float* Alog = s ? Alog1 : Alog0;
    const float* Dsk = s ? Dsk1 : Dsk0;
    unsigned short* gated = s ? g1 : g0;
    float A[4][4];
#pragma unroll
    for (int j = 0; j < 4; j++)
#pragma unroll
        for (int n = 0; n < 4; n++) A[j][n] = -__expf(Alog[(d0 + j) * 4 + n]);
    float Dv[4] = {Dsk[d0], Dsk[d0 + 1], Dsk[d0 + 2], Dsk[d0 + 3]};
    float h[4][4];
    size_t base = ((size_t)(s * 2 + b) * CH + c) * CDIM + d0;
#pragma unroll
    for (int j = 0; j < 4; j++) {
        const float* hi = hinit + (base + j) * 4;
#pragma unroll
        for (int n = 0; n < 4; n++) h[j][n] = hi[n];
    }
    int rowb = b * LDIM + c * LC;
    for (int t = 0; t < LC; t++) {
        int row = rowb + t;
        bf16x4 up = *(const bf16x4*)&u[(size_t)row * CDIM + d0];
        bf16x4 dtp = *(const bf16x4*)&dt[(size_t)row * CDIM + d0];
        bf16x4 zp = *(const bf16x4*)&uzb[(size_t)row * (2 * CDIM) + CDIM + d0];
        const float* bm = dbl + (size_t)row * 8;
        const float* cm = dblO + (size_t)row * 8 + 4;
        bf16x4 outp;
#pragma unroll
        for (int j = 0; j < 4; j++) {
            float uv = bf2f((unsigned short)up[j]);
            float dtv = bf2f((unsigned short)dtp[j]);
            float zv = bf2f((unsigned short)zp[j]);
            float du = dtv * uv;
            float y = 0.f;
#pragma unroll
            for (int n = 0; n < 4; n++) {
                float dA = __expf(dtv * A[j][n]);
                h[j][n] = dA * h[j][n] + du * bm[n];
                y += h[j][n] * cm[n];
            }
            y += uv * Dv[j];
            outp[j] = (short)f2bf(y * (zv * sigmoidf_(zv)));
        }
        *(bf16x4*)&gated[(size_t)row * CDIM + d0] = outp;
    }
}

extern "C" void kernel_launch(void* const* d_in, const int* in_sizes, int n_in,
                              void* d_out, int out_size, void* d_ws, size_t ws_size,
                              hipStream_t stream)
{
    const float* x[2] = {(const float*)d_in[0], (const float*)d_in[1]};
    const float *ln_g[2], *ln_b[2], *Win[2], *Wconv[2], *bconv[2], *Wxp[2],
        *Wdt[2], *bdt[2], *Alog[2], *Dskip[2], *Wout[2];
    for (int s = 0; s < 2; s++) {
        int base = 2 + s * 11;
        ln_g[s] = (const float*)d_in[base + 0];
        ln_b[s] = (const float*)d_in[base + 1];
        Win[s] = (const float*)d_in[base + 2];
        Wconv[s] = (const float*)d_in[base + 3];
        bconv[s] = (const float*)d_in[base + 4];
        Wxp[s] = (const float*)d_in[base + 5];
        Wdt[s] = (const float*)d_in[base + 6];
        bdt[s] = (const float*)d_in[base + 7];
        Alog[s] = (const float*)d_in[base + 8];
        Dskip[s] = (const float*)d_in[base + 9];
        Wout[s] = (const float*)d_in[base + 10];
    }

    const int M = BDIM * LDIM;  // 8192
    char* base = (char*)d_ws;
    auto alloc = [&](size_t bytes) {
        char* p = base;
        base += (bytes + 255) & ~(size_t)255;
        return p;
    };
    unsigned short* uzb[2] = {(unsigned short*)alloc((size_t)M * 1536 * 2),
                              (unsigned short*)alloc((size_t)M * 1536 * 2)};
    unsigned short* dtb[2] = {(unsigned short*)alloc((size_t)M * CDIM * 2),
                              (unsigned short*)alloc((size_t)M * CDIM * 2)};
    unsigned short* ub[2] = {(unsigned short*)alloc((size_t)M * CDIM * 2),
                             (unsigned short*)alloc((size_t)M * CDIM * 2)};
    unsigned short* xnb[2] = {(unsigned short*)alloc((size_t)M * CDIM * 2),
                              (unsigned short*)alloc((size_t)M * CDIM * 2)};  // reused as gated
    float* dbl[2] = {(float*)alloc((size_t)M * 8 * 4), (float*)alloc((size_t)M * 8 * 4)};
    unsigned short* WinT[2] = {(unsigned short*)alloc(1536 * 768 * 2),
                               (unsigned short*)alloc(1536 * 768 * 2)};
    unsigned short* WoutT[2] = {(unsigned short*)alloc(768 * 768 * 2),
                                (unsigned short*)alloc(768 * 768 * 2)};
    unsigned short* WcombT[2] = {(unsigned short*)alloc((size_t)NDT * 768 * 2),
                                 (unsigned short*)alloc((size_t)NDT * 768 * 2)};
    float* agg = (float*)alloc((size_t)2 * BDIM * CH * CDIM * 8 * 4);
    float* hinit = (float*)alloc((size_t)2 * BDIM * CH * CDIM * 4 * 4);
    float* stats = (float*)alloc((size_t)2 * M * 2 * 4);

    dim3 blk(256);
    dim3 blk512(512);
    const size_t SZ = (size_t)BDIM * LDIM * CDIM;

    // fused prep: LN stats + weight transposes + wcomb (one launch)
    prep_kernel<<<dim3(1744), blk, 0, stream>>>(
        x[0], x[1], stats,
        Win[0], Win[1], Wout[0], Wout[1], WinT[0], WinT[1], WoutT[0], WoutT[1],
        Wxp[0], Wdt[0], Wxp[1], Wdt[1], WcombT[0], WcombT[1]);

    // transpose + LN (pre-stores residual into d_out)
    transpose_ln_kernel<<<dim3(CDIM / 64, LDIM / 64, 4), blk, 0, stream>>>(
        x[0], x[1], ln_g[0], ln_b[0], ln_g[1], ln_b[1], stats, xnb[0], xnb[1], (float*)d_out);

    // in_proj: grid (64, 12, 2) = 1536 blocks = 2 rounds at 3 blocks/CU
    gemm_mfma<<<dim3(M / 128, 1536 / 128, 2), blk512, 0, stream>>>(
        xnb[0], xnb[1], WinT[0], WinT[1], uzb[0], uzb[1], 2 * CDIM, CDIM, 3,
        nullptr, nullptr, nullptr, nullptr);

    // depthwise conv + SiLU (both streams), 4 l's per thread -> ub bf16
    conv_silu_kernel<<<dim3((M * CDIM / 32) / 256, 2), blk, 0, stream>>>(
        uzb[0], uzb[1], Wconv[0], bconv[0], Wconv[1], bconv[1], ub[0], ub[1]);

    // dt = softplus(u @ Wcomb + bdt) -> dtb bf16; fused B/C proj (cols 768..775) -> dbl fp32
    gemm_mfma<<<dim3(M / 128, NDT / 128, 2), blk512, 0, stream>>>(
        ub[0], ub[1], WcombT[0], WcombT[1], dtb[0], dtb[1], CDIM, CDIM, 2,
        bdt[0], bdt[1], dbl[0], dbl[1]);

    // cross selective scan (3 phases); gating fused, writes bf16 gated into xnb
    scan_phaseA<<<dim3((2 * BDIM * CH * (CDIM / 4)) / 256), blk, 0, stream>>>(
        ub[0], dtb[0], dbl[0], Alog[0], ub[1], dtb[1], dbl[1], Alog[1], agg);
    scan_phaseB<<<dim3((2 * BDIM * CDIM * 4) / 256), blk, 0, stream>>>(agg, hinit);
    scan_phaseC<<<dim3((2 * BDIM * CH * (CDIM / 4)) / 256), blk, 0, stream>>>(
        ub[0], dtb[0], uzb[0], dbl[0], Alog[0], Dskip[0], xnb[0],
        ub[1], dtb[1], uzb[1], dbl[1], Alog[1], Dskip[1], xnb[1], hinit);

    // out_proj: grid (64, 6, 2) = 768 blocks = 1 round at 3 blocks/CU; adds into residual
    float* out = (float*)d_out;
    gemm_mfma<<<dim3(M / 128, CDIM / 128, 2), blk512, 0, stream>>>(
        xnb[0], xnb[1], WoutT[0], WoutT[1], out, out + SZ, CDIM, CDIM, 1,
        nullptr, nullptr, nullptr, nullptr);
}

// Round 9
// 404.531 us; speedup vs baseline: 1.0741x; 1.0741x over previous
//
#include <hip/hip_runtime.h>
#include <cmath>

#define LDIM 4096
#define CDIM 768
#define BDIM 2
#define NST 4
#define RNK 48
#define CH 64     // scan chunks per sequence
#define LC 64     // chunk length (CH*LC == LDIM)
#define NDT 896   // widened dt-GEMM N: 768 dt cols + 8 B/C cols + 120 zero pad (7 x 128)

typedef short bf16x8 __attribute__((ext_vector_type(8)));
typedef short bf16x4 __attribute__((ext_vector_type(4)));
typedef float f32x4 __attribute__((ext_vector_type(4)));

__device__ __forceinline__ float sigmoidf_(float x) { return 1.f / (1.f + __expf(-x)); }

__device__ __forceinline__ unsigned short f2bf(float f) {
    unsigned int u = __float_as_uint(f);
    u += 0x7fffu + ((u >> 16) & 1u);
    return (unsigned short)(u >> 16);
}
__device__ __forceinline__ float bf2f(unsigned short us) {
    unsigned int u = ((unsigned int)us) << 16;
    return __uint_as_float(u);
}
__device__ __forceinline__ float bf2f_lo(unsigned int p) { return __uint_as_float(p << 16); }
__device__ __forceinline__ float bf2f_hi(unsigned int p) { return __uint_as_float(p & 0xffff0000u); }

__device__ __forceinline__ void llds16(const unsigned short* g, unsigned short* l) {
    __builtin_amdgcn_global_load_lds(
        (const __attribute__((address_space(1))) unsigned int*)g,
        (__attribute__((address_space(3))) unsigned int*)l, 16, 0, 0);
}

// ---------- fused prep: stats (LN mean/rstd) + weight transposes + wcomb, one launch ----------
// grid.x partition: [0,256) stats | [256,1408) wt-transpose (24x12x4) | [1408,1744) wcomb (12x14x2)
__global__ __launch_bounds__(256) void prep_kernel(
    const float* __restrict__ x0, const float* __restrict__ x1, float* __restrict__ stats,
    const float* __restrict__ Win0, const float* __restrict__ Win1,
    const float* __restrict__ Wout0, const float* __restrict__ Wout1,
    unsigned short* __restrict__ WinT0, unsigned short* __restrict__ WinT1,
    unsigned short* __restrict__ WoutT0, unsigned short* __restrict__ WoutT1,
    const float* __restrict__ Wxp0, const float* __restrict__ Wdt0,
    const float* __restrict__ Wxp1, const float* __restrict__ Wdt1,
    unsigned short* __restrict__ Wc0, unsigned short* __restrict__ Wc1)
{
    __shared__ float smem[64 * 65];
    int bid = blockIdx.x;
    int t = threadIdx.x;

    if (bid < 256) {
        // ---- LN stats: s(1) b(1) lgroup(6)
        int s = bid >> 7;
        int b = (bid >> 6) & 1;
        int l0 = (bid & 63) * 64;
        int wave = t >> 6, lane = t & 63;
        const float* x = s ? x1 : x0;
        const float* xp = x + ((size_t)b * CDIM) * LDIM + l0 + lane;
        float sm = 0.f, sq = 0.f;
        int cbeg = wave * 192;
#pragma unroll
        for (int i0 = 0; i0 < 192; i0 += 16) {
            float v[16];
#pragma unroll
            for (int j = 0; j < 16; j++) v[j] = xp[(size_t)(cbeg + i0 + j) * LDIM];
#pragma unroll
            for (int j = 0; j < 16; j++) { sm += v[j]; sq += v[j] * v[j]; }
        }
        float* red = smem;  // [2][4][64]
        red[(0 * 4 + wave) * 64 + lane] = sm;
        red[(1 * 4 + wave) * 64 + lane] = sq;
        __syncthreads();
        if (wave == 0) {
            float s_ = red[lane] + red[64 + lane] + red[128 + lane] + red[192 + lane];
            float q_ = red[256 + lane] + red[320 + lane] + red[384 + lane] + red[448 + lane];
            float m = s_ * (1.f / CDIM);
            float var = q_ * (1.f / CDIM) - m * m;
            int idx = s * 8192 + b * LDIM + l0 + lane;
            stats[2 * idx] = m;
            stats[2 * idx + 1] = rsqrtf(var + 1e-5f);
        }
        return;
    }
    if (bid < 1408) {
        // ---- weight transpose: z=0,1 Win (768x1536)->WinT; z=2,3 Wout (768x768)->WoutT
        int b2 = bid - 256;
        int bx = b2 % 24, by = (b2 / 24) % 12, z = b2 / 288;
        const float* W = (z == 0) ? Win0 : (z == 1) ? Win1 : (z == 2) ? Wout0 : Wout1;
        unsigned short* Wt = (z == 0) ? WinT0 : (z == 1) ? WinT1 : (z == 2) ? WoutT0 : WoutT1;
        const int K = CDIM;
        const int N = (z < 2) ? 2 * CDIM : CDIM;
        if (bx * 64 >= N) return;  // block-uniform
        float (*tile)[65] = (float(*)[65])smem;
        int n0 = bx * 64, k0 = by * 64;
        int tn = t & 63, tg = t >> 6;
#pragma unroll
        for (int i = 0; i < 16; i++) {
            int kl = tg * 16 + i;
            tile[kl][tn] = W[(size_t)(k0 + kl) * N + n0 + tn];
        }
        __syncthreads();
#pragma unroll
        for (int i = 0; i < 16; i++) {
            int nl = tg * 16 + i;
            int k = k0 + tn, n = n0 + nl;
            Wt[(size_t)n * K + k] = f2bf(tile[tn][nl]);
        }
        return;
    }
    // ---- wcomb: rows 0..767 = (Wxp[:, :48] @ Wdt)^T; 768..775 = Wxp B/C cols; 776..895 = 0
    {
        int b3 = bid - 1408;
        int bx = b3 % 12, by = (b3 / 12) % 14, s = b3 / 168;
        const float* Wxp = s ? Wxp1 : Wxp0;
        const float* Wdt = s ? Wdt1 : Wdt0;
        unsigned short* WcombT = s ? Wc1 : Wc0;
        int k = bx * 64 + (t & 63);
        int n0 = by * 64;
        float wx[RNK];
#pragma unroll
        for (int r = 0; r < RNK; r++) wx[r] = Wxp[k * 56 + r];
        for (int i = (t >> 6); i < 64; i += 4) {
            int n = n0 + i;
            float val;
            if (n < CDIM) {
                float acc = 0.f;
#pragma unroll
                for (int r = 0; r < RNK; r++) acc += wx[r] * Wdt[(size_t)r * CDIM + n];
                val = acc;
            } else if (n < CDIM + 8) {
                val = Wxp[k * 56 + RNK + (n - CDIM)];
            } else {
                val = 0.f;
            }
            WcombT[(size_t)n * CDIM + k] = f2bf(val);
        }
    }
}

// ---------- transpose + LN: x (B,C,L) -> xn bf16 (B*L, C); raw x -> d_out (residual pre-store) ----------
// float4 global loads; write phase: 4 consecutive c per thread -> f32x4 residual + bf16x4 xn stores
// (8 wide stores/thread vs 32 scalar). LDS reads stride-260 over 16 lanes = 2-way aliasing (free).
__global__ __launch_bounds__(256) void transpose_ln_kernel(
    const float* __restrict__ x0, const float* __restrict__ x1,
    const float* __restrict__ g0, const float* __restrict__ bb0,
    const float* __restrict__ g1, const float* __restrict__ bb1,
    const float* __restrict__ stats,
    unsigned short* __restrict__ xnb0, unsigned short* __restrict__ xnb1,
    float* __restrict__ out)
{
    __shared__ float tile[64][65];  // [c][l]
    int t = threadIdx.x;
    int c0 = blockIdx.x * 64, l0 = blockIdx.y * 64;
    int z = blockIdx.z;
    int s = z >> 1, b = z & 1;
    const float* x = s ? x1 : x0;
    const float* g = s ? g1 : g0;
    const float* bb = s ? bb1 : bb0;
    unsigned short* xnb = s ? xnb1 : xnb0;
    int lane16 = t & 15, cg = t >> 4;  // 16 l-quads x 16 c-groups
#pragma unroll
    for (int i = 0; i < 4; i++) {
        int cl = cg + 16 * i;
        f32x4 v = *(const f32x4*)&x[((size_t)(b * CDIM + c0 + cl)) * LDIM + l0 + lane16 * 4];
#pragma unroll
        for (int j = 0; j < 4; j++) tile[cl][lane16 * 4 + j] = v[j];
    }
    __syncthreads();
    const size_t SZ = (size_t)BDIM * LDIM * CDIM;
    int c4 = (t & 15) * 4, lg = t >> 4;  // c-quad, 16 l-slots
    f32x4 gv = *(const f32x4*)&g[c0 + c4];
    f32x4 bv = *(const f32x4*)&bb[c0 + c4];
#pragma unroll
    for (int i = 0; i < 4; i++) {
        int ll = lg + 16 * i;
        int l = l0 + ll;
        int sidx = s * 8192 + b * LDIM + l;
        float m = stats[sidx * 2], rs = stats[sidx * 2 + 1];
        f32x4 rv;
        bf16x4 nv;
#pragma unroll
        for (int j = 0; j < 4; j++) {
            float v = tile[c4 + j][ll];
            rv[j] = v;
            nv[j] = (short)f2bf((v - m) * rs * gv[j] + bv[j]);
        }
        size_t o = ((size_t)(b * LDIM + l)) * CDIM + c0 + c4;
        *(f32x4*)&out[(size_t)s * SZ + o] = rv;   // residual pre-store
        *(bf16x4*)&xnb[o] = nv;
    }
}

// ---------- bf16 MFMA GEMM: the measured-best (74us in_proj) config, unchanged from R7/R8 ----------
// 512 threads, 8 waves (2M x 4N) of 64x32; 128x128 tile; BK=32; 3-stage pipeline; 48KB LDS
// -> 3 blocks/CU (measured: 46% occupancy, 40 VGPR, 0 bank conflicts).
// Counted vmcnt exact: at iter top outstanding = tiles i,i+1 (4 loads); vmcnt(2) drains tile i
// while i+1 stays in flight; barrier publishes; ISSUE(i+2) overwrites stage whose reads drained.
// Swizzle (HW-verified, 0 conflicts): slot chunk = global chunk ^ ((row>>1)&3).
__global__ __launch_bounds__(512, 4) void gemm_mfma(
    const unsigned short* __restrict__ A0, const unsigned short* __restrict__ A1,
    const unsigned short* __restrict__ Bt0, const unsigned short* __restrict__ Bt1,
    void* __restrict__ C0, void* __restrict__ C1, int ldc, int K, int epi,
    const float* __restrict__ bias0, const float* __restrict__ bias1,
    float* __restrict__ D0, float* __restrict__ D1)
{
    const unsigned short* A = blockIdx.z ? A1 : A0;
    const unsigned short* Bt = blockIdx.z ? Bt1 : Bt0;
    void* C = blockIdx.z ? C1 : C0;
    const float* bias = blockIdx.z ? bias1 : bias0;
    float* D = blockIdx.z ? D1 : D0;

    __shared__ unsigned short As[3][128 * 32];
    __shared__ unsigned short Bs[3][128 * 32];
    const int tid = threadIdx.x;
    const int wave = tid >> 6, lane = tid & 63;
    const int row0 = blockIdx.x * 128, col0 = blockIdx.y * 128;
    const int wm = (wave >> 2) * 64, wn = (wave & 3) * 32;   // 2x4 wave grid, 64x32 per wave
    f32x4 acc[4][2] = {};
    const int lr = lane >> 2;                                // staging row within wave's 16
    const int gi = ((lane & 3) ^ ((lane >> 3) & 3)) * 8;     // swizzled global k-chunk
    const int fr = lane & 15, fc = lane >> 4;                // fragment row / k-chunk

    const unsigned short* ga0 = A + (size_t)(row0 + wave * 16 + lr) * K + gi;
    const unsigned short* gb0 = Bt + (size_t)(col0 + wave * 16 + lr) * K + gi;
    const int rb = wave * 16;

#define ISSUE(st, kb)                         \
    do {                                      \
        llds16(ga0 + (kb), &As[st][rb * 32]); \
        llds16(gb0 + (kb), &Bs[st][rb * 32]); \
    } while (0)

    const int NIT = K / 32;
    ISSUE(0, 0);
    ISSUE(1, 32);
    for (int i = 0; i < NIT; i++) {
        if (i < NIT - 1) __builtin_amdgcn_s_waitcnt(0xF72);  // vmcnt(2): tile i landed, i+1 in flight
        else __builtin_amdgcn_s_waitcnt(0xF70);              // vmcnt(0): last tile
        __builtin_amdgcn_s_barrier();
        if (i + 2 < NIT) ISSUE((i + 2) % 3, (i + 2) * 32);
        const unsigned short* as = As[i % 3];
        const unsigned short* bs = Bs[i % 3];
        bf16x8 af[4], bfr[2];
#pragma unroll
        for (int ii = 0; ii < 4; ii++) {
            int r = wm + ii * 16 + fr;
            af[ii] = *(const bf16x8*)&as[r * 32 + (fc ^ ((r >> 1) & 3)) * 8];
        }
#pragma unroll
        for (int j = 0; j < 2; j++) {
            int r = wn + j * 16 + fr;
            bfr[j] = *(const bf16x8*)&bs[r * 32 + (fc ^ ((r >> 1) & 3)) * 8];
        }
#pragma unroll
        for (int ii = 0; ii < 4; ii++)
#pragma unroll
            for (int j = 0; j < 2; j++)
                acc[ii][j] = __builtin_amdgcn_mfma_f32_16x16x32_bf16(af[ii], bfr[j], acc[ii][j], 0, 0, 0);
    }
#undef ISSUE

    const int cr = (lane >> 4) * 4, cc = lane & 15;
#pragma unroll
    for (int ii = 0; ii < 4; ii++)
#pragma unroll
        for (int j = 0; j < 2; j++) {
            int col = col0 + wn + j * 16 + cc;
#pragma unroll
            for (int r = 0; r < 4; r++) {
                int row = row0 + wm + ii * 16 + cr + r;
                float v = acc[ii][j][r];
                if (epi == 1) {
                    float* Cf = (float*)C;
                    size_t o = (size_t)row * ldc + col;
                    Cf[o] = v + Cf[o];
                } else if (epi == 2) {
                    if (col < CDIM) {
                        v += bias[col];
                        v = (v > 20.f) ? v : __logf(1.f + __expf(v));
                        ((unsigned short*)C)[(size_t)row * ldc + col] = f2bf(v);
                    } else if (col < CDIM + 8) {
                        D[(size_t)row * 8 + (col - CDIM)] = v;  // fused B/C projection -> dbl
                    }
                } else {
                    ((unsigned short*)C)[(size_t)row * ldc + col] = f2bf(v);
                }
            }
        }
}

// ---------- depthwise causal conv (K=4) + SiLU; 4 l's x 8 d's per thread ----------
// Tap-row register reuse: 7 row-loads produce 4 outputs (1.75 loads/output vs 4 before).
__global__ __launch_bounds__(256) void conv_silu_kernel(
    const unsigned short* __restrict__ uzb0, const unsigned short* __restrict__ uzb1,
    const float* __restrict__ w0, const float* __restrict__ bc0,
    const float* __restrict__ w1, const float* __restrict__ bc1,
    unsigned short* __restrict__ ub0, unsigned short* __restrict__ ub1)
{
    int s = blockIdx.y;
    const unsigned short* uzb = s ? uzb1 : uzb0;
    const float* w = s ? w1 : w0;
    const float* bc = s ? bc1 : bc0;
    unsigned short* ub = s ? ub1 : ub0;
    int idx = blockIdx.x * 256 + threadIdx.x;  // over M*CDIM/32
    int d8 = (idx % 96) * 8;
    int bl0 = (idx / 96) * 4;
    int l0 = bl0 & (LDIM - 1);

    float wr[8][4];
#pragma unroll
    for (int q = 0; q < 8; q++) {
        f32x4 wv = *(const f32x4*)&w[(d8 + q) * 4];
#pragma unroll
        for (int k = 0; k < 4; k++) wr[q][k] = wv[k];
    }
    f32x4 b0 = *(const f32x4*)&bc[d8];
    f32x4 b1 = *(const f32x4*)&bc[d8 + 4];

    // tap rows j=0..6 correspond to token bl0-3+j; j>=3 always in-bounds
    bf16x8 rows[7];
#pragma unroll
    for (int j = 0; j < 7; j++) {
        int ls = l0 - 3 + j;
        if (ls >= 0)
            rows[j] = *(const bf16x8*)&uzb[(size_t)(bl0 - 3 + j) * (2 * CDIM) + d8];
        else
            rows[j] = bf16x8{};
    }

#pragma unroll
    for (int li = 0; li < 4; li++) {
        float acc[8];
#pragma unroll
        for (int q = 0; q < 4; q++) { acc[q] = b0[q]; acc[4 + q] = b1[q]; }
#pragma unroll
        for (int k = 0; k < 4; k++) {
#pragma unroll
            for (int q = 0; q < 8; q++)
                acc[q] += bf2f((unsigned short)rows[li + k][q]) * wr[q][k];
        }
        bf16x8 ov;
#pragma unroll
        for (int q = 0; q < 8; q++) {
            float v = acc[q];
            ov[q] = (short)f2bf(v * sigmoidf_(v));
        }
        *(bf16x8*)&ub[(size_t)(bl0 + li) * CDIM + d8] = ov;
    }
}

// ---------- chunked selective scan; u/dt/z bf16, 2 d's per thread (R7-proven: 384 blocks) ----------
__global__ __launch_bounds__(256) void scan_phaseA(
    const unsigned short* __restrict__ u0, const unsigned short* __restrict__ dt0,
    const float* __restrict__ dbl0, const float* __restrict__ Alog0,
    const unsigned short* __restrict__ u1, const unsigned short* __restrict__ dt1,
    const float* __restrict__ dbl1, const float* __restrict__ Alog1,
    float* __restrict__ agg)
{
    int idx = blockIdx.x * 256 + threadIdx.x;  // over 2*2*64*384
    int dp = idx % 384;
    int d0 = dp * 2;
    int t1 = idx / 384;
    int c = t1 % CH;
    int t2 = t1 / CH;
    int b = t2 & 1;
    int s = t2 >> 1;
    const unsigned short* u = s ? u1 : u0;
    const unsigned short* dt = s ? dt1 : dt0;
    const float* dbl = s ? dbl1 : dbl0;
    const float* Alog = s ? Alog1 : Alog0;
    float A[2][4];
#pragma unroll
    for (int j = 0; j < 2; j++)
#pragma unroll
        for (int n = 0; n < 4; n++) A[j][n] = -__expf(Alog[(d0 + j) * 4 + n]);
    float h[2][4] = {}, aa[2][4];
#pragma unroll
    for (int j = 0; j < 2; j++)
#pragma unroll
        for (int n = 0; n < 4; n++) aa[j][n] = 1.f;
    int rowb = b * LDIM + c * LC;
    for (int t = 0; t < LC; t++) {
        int row = rowb + t;
        unsigned int up = *(const unsigned int*)&u[(size_t)row * CDIM + d0];
        unsigned int dp2 = *(const unsigned int*)&dt[(size_t)row * CDIM + d0];
        float uv[2] = {bf2f_lo(up), bf2f_hi(up)};
        float dtv[2] = {bf2f_lo(dp2), bf2f_hi(dp2)};
        const float* bm = dbl + (size_t)row * 8;
#pragma unroll
        for (int j = 0; j < 2; j++) {
            float du = dtv[j] * uv[j];
#pragma unroll
            for (int n = 0; n < 4; n++) {
                float dA = __expf(dtv[j] * A[j][n]);
                h[j][n] = dA * h[j][n] + du * bm[n];
                aa[j][n] *= dA;
            }
        }
    }
    size_t base = ((size_t)(s * 2 + b) * CH + c) * CDIM + d0;
#pragma unroll
    for (int j = 0; j < 2; j++) {
        float* o = agg + (base + j) * 8;
#pragma unroll
        for (int n = 0; n < 4; n++) { o[n] = aa[j][n]; o[4 + n] = h[j][n]; }
    }
}

// one thread per (sb, d, n): 12288 threads / 48 blocks (4x the parallelism of per-(sb,d))
__global__ __launch_bounds__(256) void scan_phaseB(const float* __restrict__ agg,
                                                   float* __restrict__ hinit)
{
    int idx = blockIdx.x * 256 + threadIdx.x;  // over 4*768*4
    int n = idx & 3;
    int d = (idx >> 2) % CDIM;
    int sb = idx / (CDIM * 4);
    float st = 0.f;
    for (int c = 0; c < CH; c++) {
        size_t base = ((size_t)sb * CH + c) * CDIM + d;
        hinit[base * 4 + n] = st;
        st = agg[base * 8 + n] * st + agg[base * 8 + 4 + n];
    }
}

__global__ __launch_bounds__(256) void scan_phaseC(
    const unsigned short* __restrict__ u0, const unsigned short* __restrict__ dt0,
    const unsigned short* __restrict__ uzb0, const float* __restrict__ dbl0,
    const float* __restrict__ Alog0, const float* __restrict__ Dsk0, unsigned short* __restrict__ g0,
    const unsigned short* __restrict__ u1, const unsigned short* __restrict__ dt1,
    const unsigned short* __restrict__ uzb1, const float* __restrict__ dbl1,
    const float* __restrict__ Alog1, const float* __restrict__ Dsk1, unsigned short* __restrict__ g1,
    const float* __restrict__ hinit)
{
    int idx = blockIdx.x * 256 + threadIdx.x;  // over 2*2*64*384
    int dp = idx % 384;
    int d0 = dp * 2;
    int t1 = idx / 384;
    int c = t1 % CH;
    int t2 = t1 / CH;
    int b = t2 & 1;
    int s = t2 >> 1;
    const unsigned short* u = s ? u1 : u0;
    const unsigned short* dt = s ? dt1 : dt0;
    const unsigned short* uzb = s ? uzb1 : uzb0;
    const float* dbl = s ? dbl1 : dbl0;
    const float* dblO = s ? dbl0 : dbl1;  // cross: other stream's C projection
    const float* Alog = s ? Alog1 : Alog0;
    const float* Dsk = s ? Dsk1 : Dsk0;
    unsigned short* gated = s ? g1 : g0;
    float A[2][4];
#pragma unroll
    for (int j = 0; j < 2; j++)
#pragma unroll
        for (int n = 0; n < 4; n++) A[j][n] = -__expf(Alog[(d0 + j) * 4 + n]);
    float Dv[2] = {Dsk[d0], Dsk[d0 + 1]};
    float h[2][4];
    size_t base = ((size_t)(s * 2 + b) * CH + c) * CDIM + d0;
#pragma unroll
    for (int j = 0; j < 2; j++) {
        const float* hi = hinit + (base + j) * 4;
#pragma unroll
        for (int n = 0; n < 4; n++) h[j][n] = hi[n];
    }
    int rowb = b * LDIM + c * LC;
    for (int t = 0; t < LC; t++) {
        int row = rowb + t;
        unsigned int up = *(const unsigned int*)&u[(size_t)row * CDIM + d0];
        unsigned int dp2 = *(const unsigned int*)&dt[(size_t)row * CDIM + d0];
        unsigned int zp = *(const unsigned int*)&uzb[(size_t)row * (2 * CDIM) + CDIM + d0];
        float uv[2] = {bf2f_lo(up), bf2f_hi(up)};
        float dtv[2] = {bf2f_lo(dp2), bf2f_hi(dp2)};
        float zv[2] = {bf2f_lo(zp), bf2f_hi(zp)};
        const float* bm = dbl + (size_t)row * 8;
        const float* cm = dblO + (size_t)row * 8 + 4;
        unsigned int outp = 0;
#pragma unroll
        for (int j = 0; j < 2; j++) {
            float du = dtv[j] * uv[j];
            float y = 0.f;
#pragma unroll
            for (int n = 0; n < 4; n++) {
                float dA = __expf(dtv[j] * A[j][n]);
                h[j][n] = dA * h[j][n] + du * bm[n];
                y += h[j][n] * cm[n];
            }
            y += uv[j] * Dv[j];
            unsigned short gb = f2bf(y * (zv[j] * sigmoidf_(zv[j])));
            outp |= ((unsigned int)gb) << (16 * j);
        }
        *(unsigned int*)&gated[(size_t)row * CDIM + d0] = outp;
    }
}

extern "C" void kernel_launch(void* const* d_in, const int* in_sizes, int n_in,
                              void* d_out, int out_size, void* d_ws, size_t ws_size,
                              hipStream_t stream)
{
    const float* x[2] = {(const float*)d_in[0], (const float*)d_in[1]};
    const float *ln_g[2], *ln_b[2], *Win[2], *Wconv[2], *bconv[2], *Wxp[2],
        *Wdt[2], *bdt[2], *Alog[2], *Dskip[2], *Wout[2];
    for (int s = 0; s < 2; s++) {
        int base = 2 + s * 11;
        ln_g[s] = (const float*)d_in[base + 0];
        ln_b[s] = (const float*)d_in[base + 1];
        Win[s] = (const float*)d_in[base + 2];
        Wconv[s] = (const float*)d_in[base + 3];
        bconv[s] = (const float*)d_in[base + 4];
        Wxp[s] = (const float*)d_in[base + 5];
        Wdt[s] = (const float*)d_in[base + 6];
        bdt[s] = (const float*)d_in[base + 7];
        Alog[s] = (const float*)d_in[base + 8];
        Dskip[s] = (const float*)d_in[base + 9];
        Wout[s] = (const float*)d_in[base + 10];
    }

    const int M = BDIM * LDIM;  // 8192
    char* base = (char*)d_ws;
    auto alloc = [&](size_t bytes) {
        char* p = base;
        base += (bytes + 255) & ~(size_t)255;
        return p;
    };
    unsigned short* uzb[2] = {(unsigned short*)alloc((size_t)M * 1536 * 2),
                              (unsigned short*)alloc((size_t)M * 1536 * 2)};
    unsigned short* dtb[2] = {(unsigned short*)alloc((size_t)M * CDIM * 2),
                              (unsigned short*)alloc((size_t)M * CDIM * 2)};
    unsigned short* ub[2] = {(unsigned short*)alloc((size_t)M * CDIM * 2),
                             (unsigned short*)alloc((size_t)M * CDIM * 2)};
    unsigned short* xnb[2] = {(unsigned short*)alloc((size_t)M * CDIM * 2),
                              (unsigned short*)alloc((size_t)M * CDIM * 2)};  // reused as gated
    float* dbl[2] = {(float*)alloc((size_t)M * 8 * 4), (float*)alloc((size_t)M * 8 * 4)};
    unsigned short* WinT[2] = {(unsigned short*)alloc(1536 * 768 * 2),
                               (unsigned short*)alloc(1536 * 768 * 2)};
    unsigned short* WoutT[2] = {(unsigned short*)alloc(768 * 768 * 2),
                                (unsigned short*)alloc(768 * 768 * 2)};
    unsigned short* WcombT[2] = {(unsigned short*)alloc((size_t)NDT * 768 * 2),
                                 (unsigned short*)alloc((size_t)NDT * 768 * 2)};
    float* agg = (float*)alloc((size_t)2 * BDIM * CH * CDIM * 8 * 4);
    float* hinit = (float*)alloc((size_t)2 * BDIM * CH * CDIM * 4 * 4);
    float* stats = (float*)alloc((size_t)2 * M * 2 * 4);

    dim3 blk(256);
    dim3 blk512(512);
    const size_t SZ = (size_t)BDIM * LDIM * CDIM;

    // fused prep: LN stats + weight transposes + wcomb (one launch)
    prep_kernel<<<dim3(1744), blk, 0, stream>>>(
        x[0], x[1], stats,
        Win[0], Win[1], Wout[0], Wout[1], WinT[0], WinT[1], WoutT[0], WoutT[1],
        Wxp[0], Wdt[0], Wxp[1], Wdt[1], WcombT[0], WcombT[1]);

    // transpose + LN (pre-stores residual into d_out)
    transpose_ln_kernel<<<dim3(CDIM / 64, LDIM / 64, 4), blk, 0, stream>>>(
        x[0], x[1], ln_g[0], ln_b[0], ln_g[1], ln_b[1], stats, xnb[0], xnb[1], (float*)d_out);

    // in_proj: grid (64, 12, 2) = 1536 blocks = 2 rounds at 3 blocks/CU
    gemm_mfma<<<dim3(M / 128, 1536 / 128, 2), blk512, 0, stream>>>(
        xnb[0], xnb[1], WinT[0], WinT[1], uzb[0], uzb[1], 2 * CDIM, CDIM, 3,
        nullptr, nullptr, nullptr, nullptr);

    // depthwise conv + SiLU (both streams), 4 l's per thread -> ub bf16
    conv_silu_kernel<<<dim3((M * CDIM / 32) / 256, 2), blk, 0, stream>>>(
        uzb[0], uzb[1], Wconv[0], bconv[0], Wconv[1], bconv[1], ub[0], ub[1]);

    // dt = softplus(u @ Wcomb + bdt) -> dtb bf16; fused B/C proj (cols 768..775) -> dbl fp32
    gemm_mfma<<<dim3(M / 128, NDT / 128, 2), blk512, 0, stream>>>(
        ub[0], ub[1], WcombT[0], WcombT[1], dtb[0], dtb[1], CDIM, CDIM, 2,
        bdt[0], bdt[1], dbl[0], dbl[1]);

    // cross selective scan (3 phases); gating fused, writes bf16 gated into xnb
    scan_phaseA<<<dim3((2 * BDIM * CH * (CDIM / 2)) / 256), blk, 0, stream>>>(
        ub[0], dtb[0], dbl[0], Alog[0], ub[1], dtb[1], dbl[1], Alog[1], agg);
    scan_phaseB<<<dim3((2 * BDIM * CDIM * 4) / 256), blk, 0, stream>>>(agg, hinit);
    scan_phaseC<<<dim3((2 * BDIM * CH * (CDIM / 2)) / 256), blk, 0, stream>>>(
        ub[0], dtb[0], uzb[0], dbl[0], Alog[0], Dskip[0], xnb[0],
        ub[1], dtb[1], uzb[1], dbl[1], Alog[1], Dskip[1], xnb[1], hinit);

    // out_proj: grid (64, 6, 2) = 768 blocks = 1 round at 3 blocks/CU; adds into residual
    float* out = (float*)d_out;
    gemm_mfma<<<dim3(M / 128, CDIM / 128, 2), blk512, 0, stream>>>(
        xnb[0], xnb[1], WoutT[0], WoutT[1], out, out + SZ, CDIM, CDIM, 1,
        nullptr, nullptr, nullptr, nullptr);
}